// Round 1
// 230.036 us; speedup vs baseline: 1.0300x; 1.0300x over previous
//
#include <hip/hip_runtime.h>
#include <hip/hip_bf16.h>
#include <math.h>

// Problem constants
#define BATCH 8
#define SEQ   2048
#define CH    512
#define ROWS  (BATCH * SEQ)   // 16384
#define INVSQ 0.044194173824159216f  // 1/sqrt(512)

// GEMM tile config for logits/read kernels: 128x128 block tile, K-step 64
#define BM 128
#define BK 32
#define TILE_ELEMS (BM * BK)   // 4096 bf16 = 8 KB (one sub-tile)
#define TP 68                  // transpose-tile pitch (2-way conflict = free)

typedef __attribute__((ext_vector_type(8))) __bf16 bf16x8;
typedef __attribute__((ext_vector_type(4))) float f32x4;

__device__ inline unsigned short f2bf(float f) {
    unsigned u = __builtin_bit_cast(unsigned, f);
    u += 0x7fffu + ((u >> 16) & 1u);   // round-to-nearest-even
    return (unsigned short)(u >> 16);
}
__device__ inline float bf2f(unsigned short s) {
    unsigned u = ((unsigned)s) << 16;
    return __builtin_bit_cast(float, u);
}

// Async-stage one 128x32 bf16 sub-tile (8 KB) from global (row stride `stride`
// elems) into LDS. Layout: row-major [128][32] unpadded. (Used by logits/read.)
__device__ __forceinline__ void stage_tile(
    const unsigned short* __restrict__ gbase, size_t stride,
    unsigned short* lds, int wave, int lane)
{
#pragma unroll
    for (int j = 0; j < 2; ++j) {
        int chunk = wave * 2 + j;                  // 0..7, 16 rows each
        int row = chunk * 16 + (lane >> 2);
        const unsigned short* g = gbase + (size_t)row * stride + ((lane & 3) << 3);
        __builtin_amdgcn_global_load_lds(
            (const __attribute__((address_space(1))) unsigned int*)g,
            (__attribute__((address_space(3))) unsigned int*)(lds + (chunk << 9)),
            16, 0, 0);
    }
}

// Load a 64-row x 32-k fragment set (4x bf16x8) from a 128x32 sub-tile.
__device__ __forceinline__ void load_frags(
    const unsigned short* lds, int w0, int l16, int quad, bf16x8* f)
{
#pragma unroll
    for (int r = 0; r < 4; ++r)
        f[r] = *(const bf16x8*)(lds + (w0 + r * 16 + l16) * BK + quad * 8);
}

// ---------------------------------------------------------------------------
// fuse_x: x fp32 [16384,512] -> out[:, :, 0:512] (fp32) AND xb (bf16).
// Also zeroes Z (blocks 0..63).
// ---------------------------------------------------------------------------
__global__ __launch_bounds__(256) void fuse_x_kernel(
    const float* __restrict__ x, unsigned short* __restrict__ xb,
    float* __restrict__ out, float* __restrict__ Z)
{
    if (blockIdx.x < 64) Z[blockIdx.x * 256 + threadIdx.x] = 0.f;
    size_t base = ((size_t)blockIdx.x * 256 + threadIdx.x) * 8;
    size_t row = base >> 9, c = base & 511;
    float4 v0 = *(const float4*)(x + base);
    float4 v1 = *(const float4*)(x + base + 4);
    float* o = out + row * 1024 + c;
    *(float4*)o = v0;
    *(float4*)(o + 4) = v1;
    alignas(16) unsigned short t[8];
    t[0] = f2bf(v0.x); t[1] = f2bf(v0.y); t[2] = f2bf(v0.z); t[3] = f2bf(v0.w);
    t[4] = f2bf(v1.x); t[5] = f2bf(v1.y); t[6] = f2bf(v1.z); t[7] = f2bf(v1.w);
    *(uint4*)(xb + base) = *(const uint4*)t;
}

// ---------------------------------------------------------------------------
// transpose_w: W fp32 [512 k][512 n] -> Wt bf16 [3][512 n][512 k]
// ---------------------------------------------------------------------------
__global__ __launch_bounds__(256) void transpose_w_kernel(
    const float* __restrict__ Wq, const float* __restrict__ Wk,
    const float* __restrict__ Wv, unsigned short* __restrict__ Wt)
{
    __shared__ unsigned short T[64 * TP];
    const int k0 = blockIdx.x * 64, n0 = blockIdx.y * 64, w = blockIdx.z;
    const float* W = (w == 0) ? Wq : (w == 1) ? Wk : Wv;
    const int tid = threadIdx.x;
#pragma unroll
    for (int i = 0; i < 2; ++i) {
        int slot = tid + i * 256;
        int kr = slot >> 3, c8 = (slot & 7) << 3;
        float4 a = *(const float4*)(W + (size_t)(k0 + kr) * CH + n0 + c8);
        float4 b = *(const float4*)(W + (size_t)(k0 + kr) * CH + n0 + c8 + 4);
        T[(c8 + 0) * TP + kr] = f2bf(a.x); T[(c8 + 1) * TP + kr] = f2bf(a.y);
        T[(c8 + 2) * TP + kr] = f2bf(a.z); T[(c8 + 3) * TP + kr] = f2bf(a.w);
        T[(c8 + 4) * TP + kr] = f2bf(b.x); T[(c8 + 5) * TP + kr] = f2bf(b.y);
        T[(c8 + 6) * TP + kr] = f2bf(b.z); T[(c8 + 7) * TP + kr] = f2bf(b.w);
    }
    __syncthreads();
#pragma unroll
    for (int i = 0; i < 2; ++i) {
        int slot = tid + i * 256;
        int nr = slot >> 3, k8 = (slot & 7) << 3;
        uint2 lo = *(const uint2*)(T + nr * TP + k8);
        uint2 hi = *(const uint2*)(T + nr * TP + k8 + 4);
        uint4 u; u.x = lo.x; u.y = lo.y; u.z = hi.x; u.w = hi.y;
        *(uint4*)(Wt + ((size_t)w * CH + n0 + nr) * CH + k0 + k8) = u;
    }
}

// ---------------------------------------------------------------------------
// transpose_v: vb bf16 [b][s][v] -> Vt bf16 [b][v][s], scaled by 1/Z[b][s].
// ---------------------------------------------------------------------------
__global__ __launch_bounds__(256) void transpose_v_kernel(
    const unsigned short* __restrict__ vb, const float* __restrict__ Z,
    unsigned short* __restrict__ Vt)
{
    __shared__ unsigned short T[64 * TP];
    const int s0 = blockIdx.x * 64, v0 = blockIdx.y * 64, b = blockIdx.z;
    const int tid = threadIdx.x;
#pragma unroll
    for (int i = 0; i < 2; ++i) {
        int slot = tid + i * 256;
        int sr = slot >> 3, c8 = (slot & 7) << 3;
        float inv = 1.0f / Z[b * SEQ + s0 + sr];
        uint4 raw = *(const uint4*)(vb + ((size_t)b * SEQ + s0 + sr) * CH + v0 + c8);
        const unsigned short* p = (const unsigned short*)&raw;
#pragma unroll
        for (int j = 0; j < 8; ++j)
            T[(c8 + j) * TP + sr] = f2bf(bf2f(p[j]) * inv);
    }
    __syncthreads();
#pragma unroll
    for (int i = 0; i < 2; ++i) {
        int slot = tid + i * 256;
        int vr = slot >> 3, s8 = (slot & 7) << 3;
        uint2 lo = *(const uint2*)(T + vr * TP + s8);
        uint2 hi = *(const uint2*)(T + vr * TP + s8 + 4);
        uint4 u; u.x = lo.x; u.y = lo.y; u.z = hi.x; u.w = hi.y;
        *(uint4*)(Vt + ((size_t)b * CH + v0 + vr) * SEQ + s0 + s8) = u;
    }
}

// ---------------------------------------------------------------------------
// qkv fused GEMM, phase-interleaved counted-vmcnt pipeline (T2+T3+T4+T5).
// C[n(weight row), m(x row)]: A = Wt [1536][512] k-major, B = xb [16384][512].
// Block tile 256(x) x 128(w), BK=32, 16 K-tiles, 8 waves (2 over w, 4 over x).
// LDS 48 KB static: A[2buf][128][32] | B[2buf][256][32], XOR-swizzled slots.
// Per K-tile 2 phases: {ds_read frags | issue 1 stage chunk | s_barrier |
// lgkmcnt(0) | setprio(1) 8xMFMA setprio(0) | (vmcnt(2) once/tile) barrier}.
// Write-after-read safety: stageA(U+1) at p1 targets the slab last read in
// p2 of U-1 (behind 2 barriers); stageB(U+2) at p2 targets the slab last
// read in p1 of U (behind p1's end barrier). Read-side: vmcnt(2) at tile end
// leaves only the newest B-chunk pair in flight => next tile's A/B landed.
// ---------------------------------------------------------------------------
#define MFMA_ROW(r, af) \
    acc[r][0] = __builtin_amdgcn_mfma_f32_16x16x32_bf16(af, b0, acc[r][0], 0, 0, 0); \
    acc[r][1] = __builtin_amdgcn_mfma_f32_16x16x32_bf16(af, b1, acc[r][1], 0, 0, 0); \
    acc[r][2] = __builtin_amdgcn_mfma_f32_16x16x32_bf16(af, b2, acc[r][2], 0, 0, 0); \
    acc[r][3] = __builtin_amdgcn_mfma_f32_16x16x32_bf16(af, b3, acc[r][3], 0, 0, 0);

__global__ __launch_bounds__(512, 2) void qkv8_kernel(
    const unsigned short* __restrict__ xb, const unsigned short* __restrict__ Wt,
    const float* __restrict__ bq, const float* __restrict__ bk,
    const float* __restrict__ bv, unsigned short* __restrict__ qkv)
{
    __shared__ unsigned short lds[24576];   // 48 KB
    const int tid = threadIdx.x;
    const int lane = tid & 63, wave = tid >> 6;
    const int waveA = wave >> 2;            // 0..1: weight strip (64 rows)
    const int waveB = wave & 3;             // 0..3: x strip (64 rows)
    const int quad = lane >> 4, l16 = lane & 15;

    // Bijective XCD swizzle: 768 = 8 XCDs x 96. XCD c owns x-tiles 8c..8c+7
    // with all 12 w-tiles -> x-tile staged once per XCD L2, reused 12x.
    int id = (int)blockIdx.x;
    id = (id & 7) * 96 + (id >> 3);
    const int xt = id / 12, wt = id - xt * 12;
    const int xrow0 = xt << 8, wrow0 = wt << 7;

    const unsigned short* __restrict__ Wg = Wt + (size_t)wrow0 * CH;
    const unsigned short* __restrict__ Xg = xb + (size_t)xrow0 * CH;

    // Staging geometry: per-thread source (pre-swizzled slot), linear LDS dest.
    const int srow = tid >> 2;                               // 0..127
    const int scol = (((tid & 3) ^ ((tid >> 3) & 3)) << 3);  // swizzled src col
    const size_t ga  = (size_t)srow * CH + scol;
    const size_t gb1 = (size_t)(srow + 128) * CH + scol;
    const int wdst = wave * 512;                             // ushort idx in slab
    // Read-side swizzle: slot = quad ^ ((row>>1)&3); strips/reps are 0 mod 4,
    // so ((row>>1)&3) == ((l16>>1)&3). 2-way bank aliasing = free.
    const int rswz = ((quad ^ ((l16 >> 1) & 3)) << 3);
    const int arow = waveA * 64 + l16;
    const int brow = waveB * 64 + l16;

    f32x4 acc[4][4] = {};

    auto stageA = [&](int V) {   // 128x32 weight slab, 1 load/thread
        if (V >= 16) return;
        const unsigned short* g = Wg + ga + V * 32;
        unsigned short* d = lds + (V & 1) * 4096 + wdst;
        __builtin_amdgcn_global_load_lds(
            (const __attribute__((address_space(1))) unsigned int*)g,
            (__attribute__((address_space(3))) unsigned int*)d, 16, 0, 0);
    };
    auto stageB = [&](int V) {   // 256x32 x slab, 2 loads/thread
        if (V >= 16) return;
        const unsigned short* g0 = Xg + ga + V * 32;
        const unsigned short* g1 = Xg + gb1 + V * 32;
        unsigned short* d = lds + 8192 + (V & 1) * 8192 + wdst;
        __builtin_amdgcn_global_load_lds(
            (const __attribute__((address_space(1))) unsigned int*)g0,
            (__attribute__((address_space(3))) unsigned int*)d, 16, 0, 0);
        __builtin_amdgcn_global_load_lds(
            (const __attribute__((address_space(1))) unsigned int*)g1,
            (__attribute__((address_space(3))) unsigned int*)(d + 4096), 16, 0, 0);
    };

    // Prologue: A0, B0, B1 in flight; wait all but newest B-pair.
    stageA(0); stageB(0); stageB(1);
    asm volatile("s_waitcnt vmcnt(2)" ::: "memory");
    __builtin_amdgcn_s_barrier();
    __builtin_amdgcn_sched_barrier(0);

#pragma unroll
    for (int U = 0; U < 16; ++U) {
        const unsigned short* Ab = lds + (U & 1) * 4096;
        const unsigned short* Bb = lds + 8192 + (U & 1) * 8192;
        bf16x8 a0, a1, b0, b1, b2, b3;
        // ---- phase 1: b0..b3 + a-reps 0,1 ----
        b0 = *(const bf16x8*)(Bb + (brow +  0) * 32 + rswz);
        b1 = *(const bf16x8*)(Bb + (brow + 16) * 32 + rswz);
        b2 = *(const bf16x8*)(Bb + (brow + 32) * 32 + rswz);
        b3 = *(const bf16x8*)(Bb + (brow + 48) * 32 + rswz);
        a0 = *(const bf16x8*)(Ab + (arow +  0) * 32 + rswz);
        a1 = *(const bf16x8*)(Ab + (arow + 16) * 32 + rswz);
        stageA(U + 1);
        __builtin_amdgcn_s_barrier();
        asm volatile("s_waitcnt lgkmcnt(0)" ::: "memory");
        __builtin_amdgcn_sched_barrier(0);
        __builtin_amdgcn_s_setprio(1);
        MFMA_ROW(0, a0);
        MFMA_ROW(1, a1);
        __builtin_amdgcn_s_setprio(0);
        __builtin_amdgcn_s_barrier();
        __builtin_amdgcn_sched_barrier(0);
        // ---- phase 2: a-reps 2,3 (b reused) ----
        a0 = *(const bf16x8*)(Ab + (arow + 32) * 32 + rswz);
        a1 = *(const bf16x8*)(Ab + (arow + 48) * 32 + rswz);
        stageB(U + 2);
        __builtin_amdgcn_s_barrier();
        asm volatile("s_waitcnt lgkmcnt(0)" ::: "memory");
        __builtin_amdgcn_sched_barrier(0);
        __builtin_amdgcn_s_setprio(1);
        MFMA_ROW(2, a0);
        MFMA_ROW(3, a1);
        __builtin_amdgcn_s_setprio(0);
        if (U <= 13)      asm volatile("s_waitcnt vmcnt(2)" ::: "memory");
        else if (U == 14) asm volatile("s_waitcnt vmcnt(0)" ::: "memory");
        __builtin_amdgcn_s_barrier();
        __builtin_amdgcn_sched_barrier(0);
    }

    const int which = wrow0 >> 9;   // uniform per block (128 | 512)
    const float* bias = (which == 0) ? bq : (which == 1) ? bk : bv;
    const float scale = (which == 0) ? INVSQ : 1.0f;
    unsigned short* outw = qkv + (size_t)which * ROWS * CH;
    const int colblk = wrow0 & 511;
#pragma unroll
    for (int r = 0; r < 4; ++r) {
        int colb = colblk + waveA * 64 + r * 16 + quad * 4;
        float4 b4 = *(const float4*)(bias + colb);
#pragma unroll
        for (int c = 0; c < 4; ++c) {
            int m = xrow0 + waveB * 64 + c * 16 + l16;
            alignas(8) unsigned short pk[4];
            pk[0] = f2bf((acc[r][c][0] + b4.x) * scale);
            pk[1] = f2bf((acc[r][c][1] + b4.y) * scale);
            pk[2] = f2bf((acc[r][c][2] + b4.z) * scale);
            pk[3] = f2bf((acc[r][c][3] + b4.w) * scale);
            *(uint2*)(outw + (size_t)m * CH + colb) = *(const uint2*)pk;
        }
    }
}
#undef MFMA_ROW

// ---------------------------------------------------------------------------
// logits, swapped: C[s][t] = k_s . q_t (q pre-scaled by INVSQ).
// E[t][s] = exp(C) if s<=t else 0, packed 4-wide in s. Z[s] via shuffle+atomic.
// Compressed 1D grid: only the 136 live (st<=tt) pairs x 8 batches = 1088.
// ---------------------------------------------------------------------------
__global__ __launch_bounds__(256) void logits_kernel(
    const unsigned short* __restrict__ qb, const unsigned short* __restrict__ kb,
    unsigned short* __restrict__ E, float* __restrict__ Z)
{
    __shared__ unsigned short As[2 * TILE_ELEMS];
    __shared__ unsigned short Bs[2 * TILE_ELEMS];
    const int id = blockIdx.x;
    const int b = id & 7;
    const int i = id >> 3;                         // 0..135 triangle index
    int tt = (int)((sqrtf(8.f * (float)i + 1.f) - 1.f) * 0.5f);
    int st = i - ((tt * (tt + 1)) >> 1);
    while (st < 0)  { --tt; st = i - ((tt * (tt + 1)) >> 1); }
    while (st > tt) { ++tt; st = i - ((tt * (tt + 1)) >> 1); }
    const int m0s = st * BM;   // s rows (M dim, from k)
    const int n0t = tt * BM;   // t cols (N dim, from q)
    const int tid = threadIdx.x;
    const int lane = tid & 63, wave = tid >> 6;
    const int wm = (wave >> 1) * 64, wn = (wave & 1) * 64;
    const int quad = lane >> 4, l16 = lane & 15;
    const unsigned short* kB = kb + (size_t)b * SEQ * CH;
    const unsigned short* qB = qb + (size_t)b * SEQ * CH;

    f32x4 acc[4][4] = {};
    for (int kk = 0; kk < CH; kk += 64) {
        stage_tile(kB + (size_t)m0s * CH + kk,      CH, As,              wave, lane);
        stage_tile(kB + (size_t)m0s * CH + kk + 32, CH, As + TILE_ELEMS, wave, lane);
        stage_tile(qB + (size_t)n0t * CH + kk,      CH, Bs,              wave, lane);
        stage_tile(qB + (size_t)n0t * CH + kk + 32, CH, Bs + TILE_ELEMS, wave, lane);
        __syncthreads();
#pragma unroll
        for (int h = 0; h < 2; ++h) {
            bf16x8 a[4], bb[4];
            load_frags(As + h * TILE_ELEMS, wm, l16, quad, a);
            load_frags(Bs + h * TILE_ELEMS, wn, l16, quad, bb);
#pragma unroll
            for (int r = 0; r < 4; ++r)
#pragma unroll
                for (int c = 0; c < 4; ++c)
                    acc[r][c] = __builtin_amdgcn_mfma_f32_16x16x32_bf16(a[r], bb[c], acc[r][c], 0, 0, 0);
        }
        __syncthreads();
    }
#pragma unroll
    for (int r = 0; r < 4; ++r) {
        int sb = m0s + wm + r * 16 + quad * 4;
        float ev[4][4];
#pragma unroll
        for (int c = 0; c < 4; ++c) {
            int t = n0t + wn + c * 16 + l16;
#pragma unroll
            for (int reg = 0; reg < 4; ++reg)
                ev[c][reg] = (sb + reg <= t) ? __expf(acc[r][c][reg]) : 0.f;
        }
#pragma unroll
        for (int reg = 0; reg < 4; ++reg) {
            float z = ev[0][reg] + ev[1][reg] + ev[2][reg] + ev[3][reg];
            z += __shfl_xor(z, 1);
            z += __shfl_xor(z, 2);
            z += __shfl_xor(z, 4);
            z += __shfl_xor(z, 8);
            if (l16 == 0) atomicAdd(&Z[b * SEQ + sb + reg], z);
        }
#pragma unroll
        for (int c = 0; c < 4; ++c) {
            int t = n0t + wn + c * 16 + l16;
            alignas(8) unsigned short pk[4];
            pk[0] = f2bf(ev[c][0]); pk[1] = f2bf(ev[c][1]);
            pk[2] = f2bf(ev[c][2]); pk[3] = f2bf(ev[c][3]);
            *(uint2*)(E + ((size_t)b * SEQ + t) * SEQ + sb) = *(const uint2*)pk;
        }
    }
}

// ---------------------------------------------------------------------------
// read, swapped: C[v][t] = sum_s Vt[v][s] * E[t][s] (causal K-loop, BK=64).
// A = Vt [b][v][s], B = E [b][t][s]. fp32 packed float4 -> out[:, :, 512+v].
// 1D grid 512, tt balance-swizzled.
// ---------------------------------------------------------------------------
__global__ __launch_bounds__(256) void read_kernel(
    const unsigned short* __restrict__ E, const unsigned short* __restrict__ Vt,
    float* __restrict__ out)
{
    __shared__ unsigned short As[2 * TILE_ELEMS];
    __shared__ unsigned short Bs[2 * TILE_ELEMS];
    const int id = blockIdx.x;
    const int b = id & 7;
    const int rem = id >> 3;
    const int mv = rem & 3;                  // v tile (4)
    const int r0 = rem >> 2;                 // 0..15
    const int tt = (r0 < 8) ? r0 : 23 - r0;  // pairs (r0, r0+8) -> tt sums to 15
    const int m0v = mv * BM;
    const int n0t = tt * BM;
    const int Kmax = (tt + 1) * BM;
    const int tid = threadIdx.x;
    const int lane = tid & 63, wave = tid >> 6;
    const int wm = (wave >> 1) * 64, wn = (wave & 1) * 64;
    const int quad = lane >> 4, l16 = lane & 15;
    const unsigned short* Vb = Vt + (size_t)b * CH * SEQ;   // [v][s]
    const unsigned short* Eb = E + (size_t)b * SEQ * SEQ;   // [t][s]

    f32x4 acc[4][4] = {};
    for (int kk = 0; kk < Kmax; kk += 64) {
        stage_tile(Vb + (size_t)m0v * SEQ + kk,      SEQ, As,              wave, lane);
        stage_tile(Vb + (size_t)m0v * SEQ + kk + 32, SEQ, As + TILE_ELEMS, wave, lane);
        stage_tile(Eb + (size_t)n0t * SEQ + kk,      SEQ, Bs,              wave, lane);
        stage_tile(Eb + (size_t)n0t * SEQ + kk + 32, SEQ, Bs + TILE_ELEMS, wave, lane);
        __syncthreads();
#pragma unroll
        for (int h = 0; h < 2; ++h) {
            bf16x8 a[4], bb[4];
            load_frags(As + h * TILE_ELEMS, wm, l16, quad, a);
            load_frags(Bs + h * TILE_ELEMS, wn, l16, quad, bb);
#pragma unroll
            for (int r = 0; r < 4; ++r)
#pragma unroll
                for (int c = 0; c < 4; ++c)
                    acc[r][c] = __builtin_amdgcn_mfma_f32_16x16x32_bf16(a[r], bb[c], acc[r][c], 0, 0, 0);
        }
        __syncthreads();
    }
#pragma unroll
    for (int r = 0; r < 4; ++r) {
        int v = 512 + m0v + wm + r * 16 + quad * 4;
#pragma unroll
        for (int c = 0; c < 4; ++c) {
            int t = n0t + wn + c * 16 + l16;
            float4 f;
            f.x = acc[r][c][0]; f.y = acc[r][c][1];
            f.z = acc[r][c][2]; f.w = acc[r][c][3];
            *(float4*)(out + ((size_t)b * SEQ + t) * 1024 + v) = f;
        }
    }
}

extern "C" void kernel_launch(void* const* d_in, const int* in_sizes, int n_in,
                              void* d_out, int out_size, void* d_ws, size_t ws_size,
                              hipStream_t stream) {
    const float* x  = (const float*)d_in[0];
    const float* Wq = (const float*)d_in[1];
    const float* bq = (const float*)d_in[2];
    const float* Wk = (const float*)d_in[3];
    const float* bk = (const float*)d_in[4];
    const float* Wv = (const float*)d_in[5];
    const float* bv = (const float*)d_in[6];
    float* out = (float*)d_out;

    char* ws = (char*)d_ws;
    const size_t QKV_BYTES = (size_t)ROWS * CH * 2;              // 16,777,216
    const size_t E_BYTES   = (size_t)BATCH * SEQ * SEQ * 2;      // 67,108,864
    unsigned short* qkv = (unsigned short*)ws;                   // q,k,v contiguous
    unsigned short* qb = qkv;
    unsigned short* kb = (unsigned short*)(ws + QKV_BYTES);
    unsigned short* vb = (unsigned short*)(ws + 2 * QKV_BYTES);
    unsigned short* E  = (unsigned short*)(ws + 3 * QKV_BYTES);
    float* Z = (float*)(ws + 3 * QKV_BYTES + E_BYTES);
    // Aliases (lifetimes disjoint on the in-order stream):
    unsigned short* xb = E;                                       // dead before logits writes E
    unsigned short* Wt = (unsigned short*)((char*)E + QKV_BYTES); // dead before logits writes E
    unsigned short* Vt = qb;                                      // qb dead after logits

    dim3 blk(256);
    fuse_x_kernel<<<dim3(4096), blk, 0, stream>>>(x, xb, out, Z);
    transpose_w_kernel<<<dim3(8, 8, 3), blk, 0, stream>>>(Wq, Wk, Wv, Wt);
    qkv8_kernel<<<dim3(768), dim3(512), 0, stream>>>(xb, Wt, bq, bk, bv, qkv);
    logits_kernel<<<dim3(1088), blk, 0, stream>>>(qb, kb, E, Z);
    transpose_v_kernel<<<dim3(32, 8, 8), blk, 0, stream>>>(vb, Z, Vt);
    read_kernel<<<dim3(512), blk, 0, stream>>>(E, Vt, out);
}